// Round 6
// baseline (661.609 us; speedup 1.0000x reference)
//
#include <hip/hip_runtime.h>
#include <hip/hip_bf16.h>

#define G 200
#define NDIM 32
#define EDIM 19
#define KIN 51  // NDIM + EDIM

typedef unsigned short u16;
typedef unsigned int u32;

typedef __attribute__((ext_vector_type(8))) short bfrag;   // 8 bf16 (4 VGPRs)
typedef __attribute__((ext_vector_type(4))) float ffrag;   // 4 fp32 acc

__device__ __forceinline__ float lrelu(float x){ return x > 0.f ? x : 0.01f*x; }
__device__ __forceinline__ u16 f2b(float x){ u32 u = __float_as_uint(x); return (u16)((u + 0x7fffu + ((u >> 16) & 1u)) >> 16); }
__device__ __forceinline__ float b2f(u16 x){ return __uint_as_float(((u32)x) << 16); }

// ---------------- zero: s_raw [N*G], denom, deg ----------------
__global__ void zero_kernel(float* __restrict__ s_raw, float* __restrict__ denom,
                            int* __restrict__ deg, int N){
  int i = blockIdx.x * 256 + threadIdx.x;
  if (i < N * G) s_raw[i] = 0.f;
  if (i < N){ denom[i] = 0.f; deg[i] = 0; }
}

// ---------------- generic weight prep: W [Nr][Kc] fp32 -> Wb [Npad][Kpad] bf16 ----------------
__global__ void prep_w_kernel(const float* __restrict__ W, u16* __restrict__ Wb,
                              int Nr, int Kc, int Npad, int Kpad){
  int idx = blockIdx.x * 256 + threadIdx.x;
  if (idx < Npad * Kpad){
    int r = idx / Kpad, k = idx % Kpad;
    float v = (r < Nr && k < Kc) ? W[r * Kc + k] : 0.f;
    Wb[idx] = f2b(v);
  }
}

// ---------------- degree histogram ----------------
__global__ void deghist_kernel(const int* __restrict__ dst, int* __restrict__ deg, int E){
  int e = blockIdx.x * 256 + threadIdx.x;
  if (e < E) atomicAdd(&deg[dst[e]], 1);
}

// ---------------- l1[n] = dot(We2[0:200], hv[n]) ----------------
__global__ __launch_bounds__(256) void l1_kernel(const float* __restrict__ hv, const float* __restrict__ We2,
                                                 float* __restrict__ l1, int N){
  int wv = (blockIdx.x * 256 + threadIdx.x) >> 6;
  int lane = threadIdx.x & 63;
  if (wv >= N) return;
  float p = 0.f;
  for (int g = lane; g < G; g += 64) p += We2[g] * hv[(long)wv * G + g];
  #pragma unroll
  for (int off = 32; off; off >>= 1) p += __shfl_down(p, off, 64);
  if (lane == 0) l1[wv] = p;
}

// ---------------- single-block exclusive scan (CSR offsets) ----------------
__global__ __launch_bounds__(1024) void scan_kernel(const int* __restrict__ deg, int* __restrict__ offs,
                                                    int* __restrict__ cur, int N){
  __shared__ int wsums[16];
  __shared__ int carry_s;
  int tid = threadIdx.x;
  int lane = tid & 63, wid = tid >> 6;
  if (tid == 0) carry_s = 0;
  __syncthreads();
  for (int base = 0; base < N; base += 1024){
    int i = base + tid;
    int v = (i < N) ? deg[i] : 0;
    int x = v;
    #pragma unroll
    for (int off = 1; off < 64; off <<= 1){
      int y = __shfl_up(x, off, 64);
      if (lane >= off) x += y;
    }
    if (lane == 63) wsums[wid] = x;
    __syncthreads();
    if (wid == 0){
      int w = (lane < 16) ? wsums[lane] : 0;
      #pragma unroll
      for (int off = 1; off < 16; off <<= 1){
        int y = __shfl_up(w, off, 64);
        if (lane >= off) w += y;
      }
      if (lane < 16) wsums[lane] = w;
    }
    __syncthreads();
    int wexcl = (wid == 0) ? 0 : wsums[wid - 1];
    int incl = carry_s + wexcl + x;
    if (i < N){ offs[i] = incl - v; cur[i] = incl - v; }
    __syncthreads();
    if (tid == 1023) carry_s = incl;
    __syncthreads();
  }
  if (threadIdx.x == 0) offs[N] = carry_s;
}

// ---------------- scatter: CSR edge ids + compacted dst ----------------
__global__ void scatter_kernel(const int* __restrict__ dst, int* __restrict__ cur,
                               int* __restrict__ eids, int* __restrict__ dstc, int E){
  int e = blockIdx.x * 256 + threadIdx.x;
  if (e < E){
    int d = dst[e];
    int pos = atomicAdd(&cur[d], 1);
    eids[pos] = e;
    dstc[pos] = d;
  }
}

// ---------------- A-resident wide MFMA GEMM ----------------
// C = act(A[M,K] @ W^T + bias). W pre-padded bf16 [Npad][KC*64].
// ACT: 0 none, 1 lrelu, 2 elu with per-row 1/denom scaling of A and bias gate (denom>0).
// Block: 256 threads, 64 rows; loops NT n-tiles of 64 starting at blockIdx.y*NT.
template<int ACT, int KC>
__global__ __launch_bounds__(256) void mgemm_wide_kernel(
    const float* __restrict__ A, const u16* __restrict__ Wb, const float* __restrict__ bias,
    const float* __restrict__ denom, float* __restrict__ C,
    int M, int K, int Nout, int NT)
{
  __shared__ __align__(16) u16 As[64][KC * 64 + 8];
  __shared__ float invd[64];
  int tid = threadIdx.x;
  int m0 = blockIdx.x * 64;
  if (ACT == 2){
    if (tid < 64){
      float dn = (m0 + tid < M) ? denom[m0 + tid] : 0.f;
      invd[tid] = dn > 0.f ? 1.f / dn : 0.f;
    }
    __syncthreads();
  }
  for (int idx = tid; idx < 64 * KC * 16; idx += 256){
    int r = idx / (KC * 16), c4 = idx % (KC * 16);
    int row = m0 + r, k = c4 * 4;
    float4 v = make_float4(0.f,0.f,0.f,0.f);
    if (row < M && k < K) v = *(const float4*)(A + (long)row * K + k);
    if (ACT == 2){ float iv = invd[r]; v.x *= iv; v.y *= iv; v.z *= iv; v.w *= iv; }
    *(ushort4*)&As[r][c4 * 4] = make_ushort4(f2b(v.x), f2b(v.y), f2b(v.z), f2b(v.w));
  }
  __syncthreads();
  int l = tid & 63, w = tid >> 6, quad = l >> 4, col = l & 15;
  bfrag a[2 * KC];
  #pragma unroll
  for (int j = 0; j < 2 * KC; ++j) a[j] = *(const bfrag*)&As[w * 16 + col][j * 32 + quad * 8];

  int nt0 = blockIdx.y * NT;
  int ntmax = (Nout + 63) >> 6;
  for (int nt = nt0; nt < nt0 + NT && nt < ntmax; ++nt){
    int n0 = nt * 64;
    ffrag acc[4];
    #pragma unroll
    for (int t = 0; t < 4; ++t){ acc[t].x = 0.f; acc[t].y = 0.f; acc[t].z = 0.f; acc[t].w = 0.f; }
    #pragma unroll
    for (int j = 0; j < 2 * KC; ++j){
      #pragma unroll
      for (int t = 0; t < 4; ++t){
        bfrag b = *(const bfrag*)(Wb + (long)(n0 + t * 16 + col) * (KC * 64) + j * 32 + quad * 8);
        acc[t] = __builtin_amdgcn_mfma_f32_16x16x32_bf16(a[j], b, acc[t], 0, 0, 0);
      }
    }
    #pragma unroll
    for (int t = 0; t < 4; ++t){
      int n = n0 + t * 16 + col;
      if (n >= Nout) continue;
      float bv = bias[n];
      #pragma unroll
      for (int r = 0; r < 4; ++r){
        int lrow = w * 16 + quad * 4 + r;
        int row = m0 + lrow;
        if (row >= M) continue;
        float v;
        if (ACT == 2){
          float bf = (invd[lrow] > 0.f) ? 1.f : 0.f;
          v = acc[t][r] + bf * bv;
          v = (v > 0.f) ? v : (__expf(v) - 1.f);
        } else {
          v = acc[t][r] + bv;
          if (ACT == 1) v = lrelu(v);
        }
        C[(long)row * Nout + n] = v;
      }
    }
  }
}

// ---------------- CSR-ordered edge kernel: he1 (registers) + logit + exp + LDS segment-reduce ----------------
// block = 256 threads (4 waves), 64 CSR positions. Output: s_raw[n][g] += ex*he1, denom[n] += ex.
// Interior segments: plain store. Block-boundary segments: atomicAdd. Column-walk carry spans 2 halves.
#define ASTR 202  // fp32 stride for 32-row staging
__global__ __launch_bounds__(256) void edge_csr_kernel(
    const float* __restrict__ nf, const float* __restrict__ ef, const int* __restrict__ src,
    const int* __restrict__ eids, const int* __restrict__ dstc, const int* __restrict__ offs,
    const u16* __restrict__ Wbg, const float* __restrict__ be1,
    const float* __restrict__ We2, const float* __restrict__ be2,
    const float* __restrict__ l1,
    float* __restrict__ s_raw, float* __restrict__ denom, int E)
{
  __shared__ __align__(16) char shm_raw[32 * ASTR * 4];  // union: Xs bf16 [64][72] (9.2 KB) / accs f32 [32][202]
  u16*   Xs   = (u16*)shm_raw;
  float* accs = (float*)shm_raw;
  __shared__ float bias_s[208], w2hi_s[208];
  __shared__ float plds[64], exs[64];
  __shared__ int node_s[64], es[64], srcs[64], flags[64];

  int tid = threadIdx.x;
  int j0 = blockIdx.x * 64;

  if (tid < 64){
    int j = j0 + tid;
    int e = (j < E) ? eids[j] : 0;
    es[tid] = e;
    node_s[tid] = (j < E) ? dstc[j] : -1;
    srcs[tid] = (j < E) ? src[e] : 0;
  }
  if (tid < 208){
    bias_s[tid] = (tid < G) ? be1[tid] : 0.f;
    w2hi_s[tid] = (tid < G) ? We2[G + tid] : 0.f;
  }
  __syncthreads();
  // X fill: nf rows (gather, float4), ef rows (gather, scalar), zero pad
  for (int idx = tid; idx < 64 * 8; idx += 256){
    int el = idx >> 3, c = idx & 7;
    float4 v = make_float4(0.f,0.f,0.f,0.f);
    if (j0 + el < E) v = *(const float4*)(nf + (long)srcs[el] * NDIM + c * 4);
    *(ushort4*)&Xs[el * 72 + c * 4] = make_ushort4(f2b(v.x), f2b(v.y), f2b(v.z), f2b(v.w));
  }
  for (int idx = tid; idx < 64 * EDIM; idx += 256){
    int el = idx / EDIM, k = idx - el * EDIM;
    float v = 0.f;
    if (j0 + el < E) v = ef[(long)es[el] * EDIM + k];
    Xs[el * 72 + NDIM + k] = f2b(v);
  }
  for (int idx = tid; idx < 64 * 13; idx += 256){
    int el = idx / 13, kk = idx - el * 13;
    Xs[el * 72 + KIN + kk] = 0;
  }
  __syncthreads();

  int l = tid & 63, w = tid >> 6;
  int quad = l >> 4, col = l & 15;
  int m0 = w * 16;

  bfrag a0 = *(const bfrag*)&Xs[(m0 + col) * 72 + quad * 8];
  bfrag a1 = *(const bfrag*)&Xs[(m0 + col) * 72 + 32 + quad * 8];

  ffrag acc[13];
  #pragma unroll
  for (int t = 0; t < 13; ++t){ acc[t].x = 0.f; acc[t].y = 0.f; acc[t].z = 0.f; acc[t].w = 0.f; }
  #pragma unroll
  for (int t = 0; t < 13; ++t){
    bfrag b0 = *(const bfrag*)(Wbg + (t * 16 + col) * 64 + quad * 8);
    bfrag b1 = *(const bfrag*)(Wbg + (t * 16 + col) * 64 + 32 + quad * 8);
    acc[t] = __builtin_amdgcn_mfma_f32_16x16x32_bf16(a0, b0, acc[t], 0, 0, 0);
    acc[t] = __builtin_amdgcn_mfma_f32_16x16x32_bf16(a1, b1, acc[t], 0, 0, 0);
  }

  // logit partials from register he1
  float pl[4] = {0.f, 0.f, 0.f, 0.f};
  #pragma unroll
  for (int t = 0; t < 13; ++t){
    int g = t * 16 + col;
    float bv = bias_s[g], wv = w2hi_s[g];
    #pragma unroll
    for (int r = 0; r < 4; ++r)
      pl[r] += wv * lrelu(acc[t][r] + bv);
  }
  #pragma unroll
  for (int r = 0; r < 4; ++r){
    pl[r] += __shfl_xor(pl[r], 1, 16);
    pl[r] += __shfl_xor(pl[r], 2, 16);
    pl[r] += __shfl_xor(pl[r], 4, 16);
    pl[r] += __shfl_xor(pl[r], 8, 16);
  }
  if (col == 0){
    #pragma unroll
    for (int r = 0; r < 4; ++r) plds[m0 + quad * 4 + r] = pl[r];
  }
  __syncthreads();
  // per-edge: exp(logit); segment flags
  if (tid < 64){
    int j = j0 + tid;
    int n = node_s[tid];
    float ex = 0.f;
    if (j < E){
      float lg = lrelu(plds[tid] + l1[n] + be2[0]);
      ex = __expf(lg);
    }
    exs[tid] = ex;
    int nxt = (tid < 63) ? node_s[tid + 1] : -2;
    int f = (n != nxt) ? 1 : 0;
    if (f && n >= 0 && offs[n] >= j0 && offs[n + 1] <= j0 + 64) f |= 2;
    flags[tid] = f;
  }
  __syncthreads();   // Xs dead beyond this point; accs region live

  // ---- Phase A: waves 0,1 stage rows 0..31 (ex-scaled fp32) ----
  if (w < 2){
    #pragma unroll
    for (int t = 0; t < 13; ++t){
      int g = t * 16 + col;
      float bv = bias_s[g];
      if (g < G){
        #pragma unroll
        for (int r = 0; r < 4; ++r){
          int el = m0 + quad * 4 + r;   // 0..31
          accs[el * ASTR + g] = lrelu(acc[t][r] + bv) * exs[el];
        }
      }
    }
  }
  if (tid < 32) accs[tid * ASTR + 200] = exs[tid];
  __syncthreads();
  // ---- Walk A (columns 0..200, carry in register) ----
  float run = 0.f;
  if (tid <= 200){
    for (int r = 0; r < 32; ++r){
      run += accs[r * ASTR + tid];
      int f = flags[r];
      if (f & 1){
        int n = node_s[r];
        if (n >= 0){
          float* pdst = (tid < G) ? (s_raw + (long)n * G + tid) : (denom + n);
          if (f & 2) *pdst = run; else atomicAdd(pdst, run);
        }
        run = 0.f;
      }
    }
  }
  __syncthreads();
  // ---- Phase B: waves 2,3 stage rows 32..63 ----
  if (w >= 2){
    #pragma unroll
    for (int t = 0; t < 13; ++t){
      int g = t * 16 + col;
      float bv = bias_s[g];
      if (g < G){
        #pragma unroll
        for (int r = 0; r < 4; ++r){
          int el = m0 + quad * 4 + r;   // 32..63
          accs[(el - 32) * ASTR + g] = lrelu(acc[t][r] + bv) * exs[el];
        }
      }
    }
  }
  if (tid < 32) accs[tid * ASTR + 200] = exs[32 + tid];
  __syncthreads();
  // ---- Walk B ----
  if (tid <= 200){
    for (int r = 0; r < 32; ++r){
      run += accs[r * ASTR + tid];
      int f = flags[32 + r];
      if (f & 1){
        int n = node_s[32 + r];
        if (n >= 0){
          float* pdst = (tid < G) ? (s_raw + (long)n * G + tid) : (denom + n);
          if (f & 2) *pdst = run; else atomicAdd(pdst, run);
        }
        run = 0.f;
      }
    }
  }
}

// ---------------- GRU gates + relu ----------------
__device__ __forceinline__ float gruc(float ir, float iz, float inn, float hr, float hz, float hn, float hvv){
  float r = 1.f / (1.f + __expf(-(ir + hr)));
  float z = 1.f / (1.f + __expf(-(iz + hz)));
  float n = tanhf(inn + r * hn);
  float h = (1.f - z) * n + z * hvv;
  return h > 0.f ? h : 0.f;
}

__global__ void gru_kernel(const float* __restrict__ gi, const float* __restrict__ gh,
                           const float* __restrict__ hv, float* __restrict__ out, int N){
  int idx = blockIdx.x * 256 + threadIdx.x;
  if (idx >= N * 50) return;
  int i = idx / 50, g = (idx % 50) * 4;
  const float* gir = gi + (long)i * 600;
  const float* ghr = gh + (long)i * 600;
  float4 ir = *(const float4*)(gir + g);
  float4 iz = *(const float4*)(gir + 200 + g);
  float4 in_ = *(const float4*)(gir + 400 + g);
  float4 hr = *(const float4*)(ghr + g);
  float4 hz = *(const float4*)(ghr + 200 + g);
  float4 hn = *(const float4*)(ghr + 400 + g);
  float4 h = *(const float4*)(hv + (long)i * 200 + g);
  float4 o;
  o.x = gruc(ir.x, iz.x, in_.x, hr.x, hz.x, hn.x, h.x);
  o.y = gruc(ir.y, iz.y, in_.y, hr.y, hz.y, hn.y, h.y);
  o.z = gruc(ir.z, iz.z, in_.z, hr.z, hz.z, hn.z, h.z);
  o.w = gruc(ir.w, iz.w, in_.w, hr.w, hz.w, hn.w, h.w);
  *(float4*)(out + (long)i * 200 + g) = o;
}

extern "C" void kernel_launch(void* const* d_in, const int* in_sizes, int n_in,
                              void* d_out, int out_size, void* d_ws, size_t ws_size,
                              hipStream_t stream)
{
  const float* nf   = (const float*)d_in[0];
  const float* ef   = (const float*)d_in[1];
  const int*   src  = (const int*)d_in[2];
  const int*   dst  = (const int*)d_in[3];
  const float* Wn   = (const float*)d_in[4];
  const float* bn   = (const float*)d_in[5];
  const float* We1  = (const float*)d_in[6];
  const float* be1  = (const float*)d_in[7];
  const float* We2  = (const float*)d_in[8];
  const float* be2  = (const float*)d_in[9];
  const float* Wet  = (const float*)d_in[10];
  const float* bet  = (const float*)d_in[11];
  const float* W_ih = (const float*)d_in[12];
  const float* b_ih = (const float*)d_in[13];
  const float* W_hh = (const float*)d_in[14];
  const float* b_hh = (const float*)d_in[15];
  int N = in_sizes[0] / NDIM;   // 25000
  int E = in_sizes[2];          // 500000
  float* out = (float*)d_out;

  char* p = (char*)d_ws;
  auto alloc = [&](size_t b){ char* r = p; p += (b + 255) & ~(size_t)255; return r; };
  float* hv    = (float*)alloc((size_t)N * G * 4);       // 20 MB
  float* s_raw = (float*)alloc((size_t)N * G * 4);       // 20 MB (unnormalized ex-weighted sums)
  float* denom = (float*)alloc((size_t)N * 4);
  int*   deg   = (int*)  alloc((size_t)N * 4);
  int*   offs  = (int*)  alloc((size_t)(N + 1) * 4);
  int*   cur   = (int*)  alloc((size_t)N * 4);
  int*   eids  = (int*)  alloc((size_t)E * 4);
  int*   dstc  = (int*)  alloc((size_t)E * 4);
  u16*   Wbg   = (u16*)  alloc((size_t)208 * 64 * 2);
  float* l1    = (float*)alloc((size_t)N * 4);
  u16*   Wnb   = (u16*)  alloc((size_t)256 * 64 * 2);
  u16*   Wetb  = (u16*)  alloc((size_t)256 * 256 * 2);
  u16*   Wihb  = (u16*)  alloc((size_t)640 * 256 * 2);
  u16*   Whhb  = (u16*)  alloc((size_t)640 * 256 * 2);
  float* ctx   = (float*)alloc((size_t)N * G * 4);       // 20 MB
  float* gi    = (float*)alloc((size_t)N * 3 * G * 4);   // 60 MB
  float* gh    = (float*)alloc((size_t)N * 3 * G * 4);   // 60 MB

  int eb = (E + 255) / 256;
  int mb = (N + 63) / 64;

  zero_kernel<<<dim3((N * G + 255) / 256), dim3(256), 0, stream>>>(s_raw, denom, deg, N);
  prep_w_kernel<<<dim3((208 * 64 + 255) / 256), dim3(256), 0, stream>>>(We1, Wbg, G, KIN, 208, 64);
  prep_w_kernel<<<dim3((256 * 64 + 255) / 256), dim3(256), 0, stream>>>(Wn, Wnb, G, NDIM, 256, 64);
  prep_w_kernel<<<dim3((256 * 256 + 255) / 256), dim3(256), 0, stream>>>(Wet, Wetb, G, G, 256, 256);
  prep_w_kernel<<<dim3((640 * 256 + 255) / 256), dim3(256), 0, stream>>>(W_ih, Wihb, 3 * G, G, 640, 256);
  prep_w_kernel<<<dim3((640 * 256 + 255) / 256), dim3(256), 0, stream>>>(W_hh, Whhb, 3 * G, G, 640, 256);
  deghist_kernel<<<dim3(eb), dim3(256), 0, stream>>>(dst, deg, E);
  scan_kernel<<<dim3(1), dim3(1024), 0, stream>>>(deg, offs, cur, N);
  scatter_kernel<<<dim3(eb), dim3(256), 0, stream>>>(dst, cur, eids, dstc, E);

  // hv = lrelu(nf @ Wn^T + bn)
  mgemm_wide_kernel<1, 1><<<dim3(mb, 1), dim3(256), 0, stream>>>(nf, Wnb, bn, nullptr, hv, N, NDIM, G, 4);
  l1_kernel<<<dim3((N * 64 + 255) / 256), dim3(256), 0, stream>>>(hv, We2, l1, N);
  // CSR edge pass: s_raw, denom
  edge_csr_kernel<<<dim3((E + 63) / 64), dim3(256), 0, stream>>>(nf, ef, src, eids, dstc, offs,
                                                                 Wbg, be1, We2, be2, l1, s_raw, denom, E);
  // context = elu((s_raw/denom) @ Wet^T + bet[deg>0])
  mgemm_wide_kernel<2, 4><<<dim3(mb, 2), dim3(256), 0, stream>>>(s_raw, Wetb, bet, denom, ctx, N, G, G, 2);
  mgemm_wide_kernel<0, 4><<<dim3(mb, 2), dim3(256), 0, stream>>>(ctx, Wihb, b_ih, nullptr, gi, N, G, 3 * G, 5);
  mgemm_wide_kernel<0, 4><<<dim3(mb, 2), dim3(256), 0, stream>>>(hv, Whhb, b_hh, nullptr, gh, N, G, 3 * G, 5);
  gru_kernel<<<dim3((N * 50 + 255) / 256), dim3(256), 0, stream>>>(gi, gh, hv, out, N);
}

// Round 7
// 586.345 us; speedup vs baseline: 1.1284x; 1.1284x over previous
//
#include <hip/hip_runtime.h>
#include <hip/hip_bf16.h>

#define G 200
#define NDIM 32
#define EDIM 19
#define KIN 51  // NDIM + EDIM

typedef unsigned short u16;
typedef unsigned int u32;

typedef __attribute__((ext_vector_type(8))) short bfrag;   // 8 bf16 (4 VGPRs)
typedef __attribute__((ext_vector_type(4))) float ffrag;   // 4 fp32 acc

__device__ __forceinline__ float lrelu(float x){ return x > 0.f ? x : 0.01f*x; }
__device__ __forceinline__ u16 f2b(float x){ u32 u = __float_as_uint(x); return (u16)((u + 0x7fffu + ((u >> 16) & 1u)) >> 16); }
__device__ __forceinline__ float b2f(u16 x){ return __uint_as_float(((u32)x) << 16); }

// ---------------- zero: s_raw [N*G], denom, deg ----------------
__global__ void zero_kernel(float* __restrict__ s_raw, float* __restrict__ denom,
                            int* __restrict__ deg, int N){
  int i = blockIdx.x * 256 + threadIdx.x;
  if (i < N * G) s_raw[i] = 0.f;
  if (i < N){ denom[i] = 0.f; deg[i] = 0; }
}

// ---------------- generic weight prep: W [Nr][Kc] fp32 -> Wb [Npad][Kpad] bf16 ----------------
__global__ void prep_w_kernel(const float* __restrict__ W, u16* __restrict__ Wb,
                              int Nr, int Kc, int Npad, int Kpad){
  int idx = blockIdx.x * 256 + threadIdx.x;
  if (idx < Npad * Kpad){
    int r = idx / Kpad, k = idx % Kpad;
    float v = (r < Nr && k < Kc) ? W[r * Kc + k] : 0.f;
    Wb[idx] = f2b(v);
  }
}

// ---------------- degree histogram ----------------
__global__ void deghist_kernel(const int* __restrict__ dst, int* __restrict__ deg, int E){
  int e = blockIdx.x * 256 + threadIdx.x;
  if (e < E) atomicAdd(&deg[dst[e]], 1);
}

// ---------------- l1[n] = dot(We2[0:200], hv[n]) ----------------
__global__ __launch_bounds__(256) void l1_kernel(const float* __restrict__ hv, const float* __restrict__ We2,
                                                 float* __restrict__ l1, int N){
  int wv = (blockIdx.x * 256 + threadIdx.x) >> 6;
  int lane = threadIdx.x & 63;
  if (wv >= N) return;
  float p = 0.f;
  for (int g = lane; g < G; g += 64) p += We2[g] * hv[(long)wv * G + g];
  #pragma unroll
  for (int off = 32; off; off >>= 1) p += __shfl_down(p, off, 64);
  if (lane == 0) l1[wv] = p;
}

// ---------------- single-block exclusive scan (CSR offsets) ----------------
__global__ __launch_bounds__(1024) void scan_kernel(const int* __restrict__ deg, int* __restrict__ offs,
                                                    int* __restrict__ cur, int N){
  __shared__ int wsums[16];
  __shared__ int carry_s;
  int tid = threadIdx.x;
  int lane = tid & 63, wid = tid >> 6;
  if (tid == 0) carry_s = 0;
  __syncthreads();
  for (int base = 0; base < N; base += 1024){
    int i = base + tid;
    int v = (i < N) ? deg[i] : 0;
    int x = v;
    #pragma unroll
    for (int off = 1; off < 64; off <<= 1){
      int y = __shfl_up(x, off, 64);
      if (lane >= off) x += y;
    }
    if (lane == 63) wsums[wid] = x;
    __syncthreads();
    if (wid == 0){
      int w = (lane < 16) ? wsums[lane] : 0;
      #pragma unroll
      for (int off = 1; off < 16; off <<= 1){
        int y = __shfl_up(w, off, 64);
        if (lane >= off) w += y;
      }
      if (lane < 16) wsums[lane] = w;
    }
    __syncthreads();
    int wexcl = (wid == 0) ? 0 : wsums[wid - 1];
    int incl = carry_s + wexcl + x;
    if (i < N){ offs[i] = incl - v; cur[i] = incl - v; }
    __syncthreads();
    if (tid == 1023) carry_s = incl;
    __syncthreads();
  }
  if (threadIdx.x == 0) offs[N] = carry_s;
}

// ---------------- scatter: CSR edge ids + compacted dst ----------------
__global__ void scatter_kernel(const int* __restrict__ dst, int* __restrict__ cur,
                               int* __restrict__ eids, int* __restrict__ dstc, int E){
  int e = blockIdx.x * 256 + threadIdx.x;
  if (e < E){
    int d = dst[e];
    int pos = atomicAdd(&cur[d], 1);
    eids[pos] = e;
    dstc[pos] = d;
  }
}

// ---------------- MFMA node GEMM (round-5 style): C = act(A[M,K] @ W^T + bias) ----------------
// ACT: 0 none, 1 lrelu, 2 elu with per-row A scaling by 1/denom and bias gate (denom>0)
template<int ACT>
__global__ __launch_bounds__(256) void mgemm_kernel(
    const float* __restrict__ A, const u16* __restrict__ Wb, const float* __restrict__ bias,
    const float* __restrict__ denom, float* __restrict__ C, int M, int K, int Nout, int Kpad)
{
  __shared__ __align__(16) u16 As[64][72];
  __shared__ __align__(16) u16 Ws[64][72];
  __shared__ float invd[64];
  int tid = threadIdx.x;
  int m0 = blockIdx.y * 64, n0 = blockIdx.x * 64;
  int l = tid & 63, w = tid >> 6, quad = l >> 4, col = l & 15;

  if (ACT == 2){
    if (tid < 64){
      float dn = (m0 + tid < M) ? denom[m0 + tid] : 0.f;
      invd[tid] = dn > 0.f ? 1.f / dn : 0.f;
    }
    __syncthreads();
  }

  ffrag acc[4];
  #pragma unroll
  for (int t = 0; t < 4; ++t){ acc[t].x = 0.f; acc[t].y = 0.f; acc[t].z = 0.f; acc[t].w = 0.f; }

  int nK = Kpad >> 6;
  for (int kc = 0; kc < nK; ++kc){
    int k0 = kc << 6;
    for (int idx = tid; idx < 64 * 16; idx += 256){
      int r = idx >> 4, c4 = idx & 15;
      int row = m0 + r, k = k0 + c4 * 4;
      float4 v = make_float4(0.f,0.f,0.f,0.f);
      if (row < M && k < K) v = *(const float4*)(A + (long)row * K + k);
      if (ACT == 2){ float iv = invd[r]; v.x *= iv; v.y *= iv; v.z *= iv; v.w *= iv; }
      *(ushort4*)&As[r][c4 * 4] = make_ushort4(f2b(v.x), f2b(v.y), f2b(v.z), f2b(v.w));
    }
    for (int idx = tid; idx < 64 * 8; idx += 256){
      int r = idx >> 3, c = idx & 7;
      *(ulonglong2*)&Ws[r][c * 8] = *(const ulonglong2*)(Wb + (long)(n0 + r) * Kpad + k0 + c * 8);
    }
    __syncthreads();
    bfrag a0 = *(const bfrag*)&As[w * 16 + col][quad * 8];
    bfrag a1 = *(const bfrag*)&As[w * 16 + col][32 + quad * 8];
    #pragma unroll
    for (int t = 0; t < 4; ++t){
      bfrag b0 = *(const bfrag*)&Ws[t * 16 + col][quad * 8];
      bfrag b1 = *(const bfrag*)&Ws[t * 16 + col][32 + quad * 8];
      acc[t] = __builtin_amdgcn_mfma_f32_16x16x32_bf16(a0, b0, acc[t], 0, 0, 0);
      acc[t] = __builtin_amdgcn_mfma_f32_16x16x32_bf16(a1, b1, acc[t], 0, 0, 0);
    }
    __syncthreads();
  }

  #pragma unroll
  for (int t = 0; t < 4; ++t){
    int n = n0 + t * 16 + col;
    if (n >= Nout) continue;
    float bv = bias[n];
    #pragma unroll
    for (int r = 0; r < 4; ++r){
      int lrow = w * 16 + quad * 4 + r;
      int row = m0 + lrow;
      if (row >= M) continue;
      float v;
      if (ACT == 2){
        float bf = (invd[lrow] > 0.f) ? 1.f : 0.f;
        v = acc[t][r] + bf * bv;
        v = (v > 0.f) ? v : (__expf(v) - 1.f);
      } else {
        v = acc[t][r] + bv;
        if (ACT == 1) v = lrelu(v);
      }
      C[(long)row * Nout + n] = v;
    }
  }
}

// ---------------- CSR edge kernel v2: 4 barriers, all-wave bf16 staging, single 64-row walk ----------------
#define SSTR 202  // u16 stride of staging rows (cols 0..199 = ex*he1 bf16; ex itself in exs[])
__global__ __launch_bounds__(256) void edge_csr_kernel(
    const float* __restrict__ nf, const float* __restrict__ ef, const int* __restrict__ src,
    const int* __restrict__ eids, const int* __restrict__ dstc, const int* __restrict__ offs,
    const u16* __restrict__ Wbg, const float* __restrict__ be1,
    const float* __restrict__ We2, const float* __restrict__ be2,
    const float* __restrict__ l1,
    float* __restrict__ s_raw, float* __restrict__ denom, int E)
{
  __shared__ __align__(16) u16 stage[64 * SSTR];  // union: Xs [64][72] bf16 during fill
  u16* Xs = stage;
  __shared__ float bias_s[208], w2hi_s[208];
  __shared__ float exs[64];
  __shared__ int node_s[64], es[64], srcs[64], flags[64];

  int tid = threadIdx.x;
  int j0 = blockIdx.x * 64;

  if (tid < 64){
    int j = j0 + tid;
    int e = (j < E) ? eids[j] : 0;
    es[tid] = e;
    node_s[tid] = (j < E) ? dstc[j] : -1;
    srcs[tid] = (j < E) ? src[e] : 0;
  }
  if (tid < 208){
    bias_s[tid] = (tid < G) ? be1[tid] : 0.f;
    w2hi_s[tid] = (tid < G) ? We2[G + tid] : 0.f;
  }
  __syncthreads();  // sync 1: node_s/es/srcs ready
  // segment flags (cross-thread node_s)
  if (tid < 64){
    int n = node_s[tid];
    int nxt = (tid < 63) ? node_s[tid + 1] : -2;
    int f = (n != nxt) ? 1 : 0;
    if (f && n >= 0 && offs[n] >= j0 && offs[n + 1] <= j0 + 64) f |= 2;
    flags[tid] = f;
  }
  // X fill: nf rows (gather, float4)
  for (int idx = tid; idx < 64 * 8; idx += 256){
    int el = idx >> 3, c = idx & 7;
    float4 v = make_float4(0.f,0.f,0.f,0.f);
    if (j0 + el < E) v = *(const float4*)(nf + (long)srcs[el] * NDIM + c * 4);
    *(ushort4*)&Xs[el * 72 + c * 4] = make_ushort4(f2b(v.x), f2b(v.y), f2b(v.z), f2b(v.w));
  }
  // ef rows (gather, coalesced within row)
  for (int idx = tid; idx < 64 * EDIM; idx += 256){
    int el = idx / EDIM, k = idx - el * EDIM;
    float v = 0.f;
    if (j0 + el < E) v = ef[(long)es[el] * EDIM + k];
    Xs[el * 72 + NDIM + k] = f2b(v);
  }
  for (int idx = tid; idx < 64 * 13; idx += 256){
    int el = idx / 13, kk = idx - el * 13;
    Xs[el * 72 + KIN + kk] = 0;
  }
  __syncthreads();  // sync 2: X ready

  int l = tid & 63, w = tid >> 6;
  int quad = l >> 4, col = l & 15;
  int m0 = w * 16;

  bfrag a0 = *(const bfrag*)&Xs[(m0 + col) * 72 + quad * 8];
  bfrag a1 = *(const bfrag*)&Xs[(m0 + col) * 72 + 32 + quad * 8];

  ffrag acc[13];
  #pragma unroll
  for (int t = 0; t < 13; ++t){ acc[t].x = 0.f; acc[t].y = 0.f; acc[t].z = 0.f; acc[t].w = 0.f; }
  #pragma unroll
  for (int t = 0; t < 13; ++t){
    bfrag b0 = *(const bfrag*)(Wbg + (t * 16 + col) * 64 + quad * 8);
    bfrag b1 = *(const bfrag*)(Wbg + (t * 16 + col) * 64 + 32 + quad * 8);
    acc[t] = __builtin_amdgcn_mfma_f32_16x16x32_bf16(a0, b0, acc[t], 0, 0, 0);
    acc[t] = __builtin_amdgcn_mfma_f32_16x16x32_bf16(a1, b1, acc[t], 0, 0, 0);
  }

  // in-register logit partials; xor-butterfly leaves the 16-group sum in EVERY lane
  float pl[4] = {0.f, 0.f, 0.f, 0.f};
  #pragma unroll
  for (int t = 0; t < 13; ++t){
    int g = t * 16 + col;
    float bv = bias_s[g], wv = w2hi_s[g];
    #pragma unroll
    for (int r = 0; r < 4; ++r)
      pl[r] += wv * lrelu(acc[t][r] + bv);
  }
  #pragma unroll
  for (int r = 0; r < 4; ++r){
    pl[r] += __shfl_xor(pl[r], 1, 16);
    pl[r] += __shfl_xor(pl[r], 2, 16);
    pl[r] += __shfl_xor(pl[r], 4, 16);
    pl[r] += __shfl_xor(pl[r], 8, 16);
  }
  // per-lane ex for its 4 edge rows
  float exv[4];
  #pragma unroll
  for (int r = 0; r < 4; ++r){
    int el = m0 + quad * 4 + r;
    float ex = 0.f;
    if (j0 + el < E){
      int n = node_s[el];
      float lg = lrelu(pl[r] + l1[n] + be2[0]);
      ex = __expf(lg);
    }
    exv[r] = ex;
  }
  __syncthreads();  // sync 3: all Xs reads complete; stage region reusable

  // all-wave staging: ex-scaled he1 in bf16
  #pragma unroll
  for (int t = 0; t < 13; ++t){
    int g = t * 16 + col;
    if (g < G){
      float bv = bias_s[g];
      #pragma unroll
      for (int r = 0; r < 4; ++r){
        int el = m0 + quad * 4 + r;
        stage[el * SSTR + g] = f2b(lrelu(acc[t][r] + bv) * exv[r]);
      }
    }
  }
  if (col == 0){
    #pragma unroll
    for (int r = 0; r < 4; ++r) exs[m0 + quad * 4 + r] = exv[r];
  }
  __syncthreads();  // sync 4: stage + exs ready

  // single 64-row segmented walk; tid 0..199 -> s_raw columns, tid 200 -> denom
  if (tid <= 200){
    float run = 0.f;
    for (int r = 0; r < 64; ++r){
      run += (tid < G) ? b2f(stage[r * SSTR + tid]) : exs[r];
      int f = flags[r];
      if (f & 1){
        int n = node_s[r];
        if (n >= 0){
          float* pd = (tid < G) ? (s_raw + (long)n * G + tid) : (denom + n);
          if (f & 2) *pd = run; else atomicAdd(pd, run);
        }
        run = 0.f;
      }
    }
  }
}

// ---------------- GRU gates + relu ----------------
__device__ __forceinline__ float gruc(float ir, float iz, float inn, float hr, float hz, float hn, float hvv){
  float r = 1.f / (1.f + __expf(-(ir + hr)));
  float z = 1.f / (1.f + __expf(-(iz + hz)));
  float n = tanhf(inn + r * hn);
  float h = (1.f - z) * n + z * hvv;
  return h > 0.f ? h : 0.f;
}

__global__ void gru_kernel(const float* __restrict__ gi, const float* __restrict__ gh,
                           const float* __restrict__ hv, float* __restrict__ out, int N){
  int idx = blockIdx.x * 256 + threadIdx.x;
  if (idx >= N * 50) return;
  int i = idx / 50, g = (idx % 50) * 4;
  const float* gir = gi + (long)i * 600;
  const float* ghr = gh + (long)i * 600;
  float4 ir = *(const float4*)(gir + g);
  float4 iz = *(const float4*)(gir + 200 + g);
  float4 in_ = *(const float4*)(gir + 400 + g);
  float4 hr = *(const float4*)(ghr + g);
  float4 hz = *(const float4*)(ghr + 200 + g);
  float4 hn = *(const float4*)(ghr + 400 + g);
  float4 h = *(const float4*)(hv + (long)i * 200 + g);
  float4 o;
  o.x = gruc(ir.x, iz.x, in_.x, hr.x, hz.x, hn.x, h.x);
  o.y = gruc(ir.y, iz.y, in_.y, hr.y, hz.y, hn.y, h.y);
  o.z = gruc(ir.z, iz.z, in_.z, hr.z, hz.z, hn.z, h.z);
  o.w = gruc(ir.w, iz.w, in_.w, hr.w, hz.w, hn.w, h.w);
  *(float4*)(out + (long)i * 200 + g) = o;
}

extern "C" void kernel_launch(void* const* d_in, const int* in_sizes, int n_in,
                              void* d_out, int out_size, void* d_ws, size_t ws_size,
                              hipStream_t stream)
{
  const float* nf   = (const float*)d_in[0];
  const float* ef   = (const float*)d_in[1];
  const int*   src  = (const int*)d_in[2];
  const int*   dst  = (const int*)d_in[3];
  const float* Wn   = (const float*)d_in[4];
  const float* bn   = (const float*)d_in[5];
  const float* We1  = (const float*)d_in[6];
  const float* be1  = (const float*)d_in[7];
  const float* We2  = (const float*)d_in[8];
  const float* be2  = (const float*)d_in[9];
  const float* Wet  = (const float*)d_in[10];
  const float* bet  = (const float*)d_in[11];
  const float* W_ih = (const float*)d_in[12];
  const float* b_ih = (const float*)d_in[13];
  const float* W_hh = (const float*)d_in[14];
  const float* b_hh = (const float*)d_in[15];
  int N = in_sizes[0] / NDIM;   // 25000
  int E = in_sizes[2];          // 500000
  float* out = (float*)d_out;

  char* p = (char*)d_ws;
  auto alloc = [&](size_t b){ char* r = p; p += (b + 255) & ~(size_t)255; return r; };
  float* hv    = (float*)alloc((size_t)N * G * 4);
  float* s_raw = (float*)alloc((size_t)N * G * 4);
  float* denom = (float*)alloc((size_t)N * 4);
  int*   deg   = (int*)  alloc((size_t)N * 4);
  int*   offs  = (int*)  alloc((size_t)(N + 1) * 4);
  int*   cur   = (int*)  alloc((size_t)N * 4);
  int*   eids  = (int*)  alloc((size_t)E * 4);
  int*   dstc  = (int*)  alloc((size_t)E * 4);
  u16*   Wbg   = (u16*)  alloc((size_t)208 * 64 * 2);
  float* l1    = (float*)alloc((size_t)N * 4);
  u16*   Wnb   = (u16*)  alloc((size_t)256 * 64 * 2);
  u16*   Wetb  = (u16*)  alloc((size_t)256 * 256 * 2);
  u16*   Wihb  = (u16*)  alloc((size_t)640 * 256 * 2);
  u16*   Whhb  = (u16*)  alloc((size_t)640 * 256 * 2);
  float* ctx   = (float*)alloc((size_t)N * G * 4);
  float* gi    = (float*)alloc((size_t)N * 3 * G * 4);
  float* gh    = (float*)alloc((size_t)N * 3 * G * 4);

  int eb = (E + 255) / 256;
  int mb = (N + 63) / 64;

  zero_kernel<<<dim3((N * G + 255) / 256), dim3(256), 0, stream>>>(s_raw, denom, deg, N);
  prep_w_kernel<<<dim3((208 * 64 + 255) / 256), dim3(256), 0, stream>>>(We1, Wbg, G, KIN, 208, 64);
  prep_w_kernel<<<dim3((256 * 64 + 255) / 256), dim3(256), 0, stream>>>(Wn, Wnb, G, NDIM, 256, 64);
  prep_w_kernel<<<dim3((256 * 256 + 255) / 256), dim3(256), 0, stream>>>(Wet, Wetb, G, G, 256, 256);
  prep_w_kernel<<<dim3((640 * 256 + 255) / 256), dim3(256), 0, stream>>>(W_ih, Wihb, 3 * G, G, 640, 256);
  prep_w_kernel<<<dim3((640 * 256 + 255) / 256), dim3(256), 0, stream>>>(W_hh, Whhb, 3 * G, G, 640, 256);
  deghist_kernel<<<dim3(eb), dim3(256), 0, stream>>>(dst, deg, E);
  scan_kernel<<<dim3(1), dim3(1024), 0, stream>>>(deg, offs, cur, N);
  scatter_kernel<<<dim3(eb), dim3(256), 0, stream>>>(dst, cur, eids, dstc, E);

  // hv = lrelu(nf @ Wn^T + bn)
  mgemm_kernel<1><<<dim3(4, mb), dim3(256), 0, stream>>>(nf, Wnb, bn, nullptr, hv, N, NDIM, G, 64);
  l1_kernel<<<dim3((N * 64 + 255) / 256), dim3(256), 0, stream>>>(hv, We2, l1, N);
  // CSR edge pass: s_raw, denom
  edge_csr_kernel<<<dim3((E + 63) / 64), dim3(256), 0, stream>>>(nf, ef, src, eids, dstc, offs,
                                                                 Wbg, be1, We2, be2, l1, s_raw, denom, E);
  // context = elu((s_raw/denom) @ Wet^T + bet[denom>0])
  mgemm_kernel<2><<<dim3(4, mb), dim3(256), 0, stream>>>(s_raw, Wetb, bet, denom, ctx, N, G, G, 256);
  mgemm_kernel<0><<<dim3(10, mb), dim3(256), 0, stream>>>(ctx, Wihb, b_ih, nullptr, gi, N, G, 3 * G, 256);
  mgemm_kernel<0><<<dim3(10, mb), dim3(256), 0, stream>>>(hv, Whhb, b_hh, nullptr, gh, N, G, 3 * G, 256);
  gru_kernel<<<dim3((N * 50 + 255) / 256), dim3(256), 0, stream>>>(gi, gh, hv, out, N);
}

// Round 8
// 495.169 us; speedup vs baseline: 1.3361x; 1.1841x over previous
//
#include <hip/hip_runtime.h>
#include <hip/hip_bf16.h>

#define G 200
#define NDIM 32
#define EDIM 19
#define KIN 51  // NDIM + EDIM

typedef unsigned short u16;
typedef unsigned int u32;

typedef __attribute__((ext_vector_type(8))) short bfrag;   // 8 bf16 (4 VGPRs)
typedef __attribute__((ext_vector_type(4))) float ffrag;   // 4 fp32 acc

__device__ __forceinline__ float lrelu(float x){ return x > 0.f ? x : 0.01f*x; }
__device__ __forceinline__ u16 f2b(float x){ u32 u = __float_as_uint(x); return (u16)((u + 0x7fffu + ((u >> 16) & 1u)) >> 16); }
__device__ __forceinline__ float b2f(u16 x){ return __uint_as_float(((u32)x) << 16); }

#define MFMA16(a, b, c) __builtin_amdgcn_mfma_f32_16x16x32_bf16(a, b, c, 0, 0, 0)

// ---------------- zero: s_raw [N*G], denom, deg ----------------
__global__ void zero_kernel(float* __restrict__ s_raw, float* __restrict__ denom,
                            int* __restrict__ deg, int N){
  int i = blockIdx.x * 256 + threadIdx.x;
  if (i < N * G) s_raw[i] = 0.f;
  if (i < N){ denom[i] = 0.f; deg[i] = 0; }
}

// ---------------- generic weight prep: W [Nr][Kc] fp32 -> Wb [Npad][Kpad] bf16 ----------------
__global__ void prep_w_kernel(const float* __restrict__ W, u16* __restrict__ Wb,
                              int Nr, int Kc, int Npad, int Kpad){
  int idx = blockIdx.x * 256 + threadIdx.x;
  if (idx < Npad * Kpad){
    int r = idx / Kpad, k = idx % Kpad;
    float v = (r < Nr && k < Kc) ? W[r * Kc + k] : 0.f;
    Wb[idx] = f2b(v);
  }
}

// ---------------- prep Wrz: [2][208][416]: k<200 -> W_ih[g*200+r][k]; 208<=k<408 -> W_hh[g*200+r][k-208] ----------------
__global__ void prep_wrz_kernel(const float* __restrict__ Wih, const float* __restrict__ Whh,
                                u16* __restrict__ W){
  int idx = blockIdx.x * 256 + threadIdx.x;
  if (idx >= 2 * 208 * 416) return;
  int g = idx / (208 * 416), rem = idx % (208 * 416);
  int r = rem / 416, k = rem % 416;
  float v = 0.f;
  if (r < 200){
    int row = g * 200 + r;
    if (k < 200) v = Wih[row * 200 + k];
    else if (k >= 208 && k < 408) v = Whh[row * 200 + (k - 208)];
  }
  W[idx] = f2b(v);
}

// ---------------- prep Winn: [208][224] = W_ih rows 400..599 (k<200) ----------------
__global__ void prep_winn_kernel(const float* __restrict__ Wih, u16* __restrict__ W){
  int idx = blockIdx.x * 256 + threadIdx.x;
  if (idx >= 208 * 224) return;
  int r = idx / 224, k = idx % 224;
  float v = (r < 200 && k < 200) ? Wih[(400 + r) * 200 + k] : 0.f;
  W[idx] = f2b(v);
}

// ---------------- prep Whn: [208][224], kk maps to global k=192+kk: W_hh rows 400..599 at k-208 ----------------
__global__ void prep_whn_kernel(const float* __restrict__ Whh, u16* __restrict__ W){
  int idx = blockIdx.x * 256 + threadIdx.x;
  if (idx >= 208 * 224) return;
  int r = idx / 224, kk = idx % 224;
  float v = (r < 200 && kk >= 16 && kk < 216) ? Whh[(400 + r) * 200 + (kk - 16)] : 0.f;
  W[idx] = f2b(v);
}

// ---------------- degree histogram ----------------
__global__ void deghist_kernel(const int* __restrict__ dst, int* __restrict__ deg, int E){
  int e = blockIdx.x * 256 + threadIdx.x;
  if (e < E) atomicAdd(&deg[dst[e]], 1);
}

// ---------------- l1[n] = dot(We2[0:200], hv[n]) ----------------
__global__ __launch_bounds__(256) void l1_kernel(const float* __restrict__ hv, const float* __restrict__ We2,
                                                 float* __restrict__ l1, int N){
  int wv = (blockIdx.x * 256 + threadIdx.x) >> 6;
  int lane = threadIdx.x & 63;
  if (wv >= N) return;
  float p = 0.f;
  for (int g = lane; g < G; g += 64) p += We2[g] * hv[(long)wv * G + g];
  #pragma unroll
  for (int off = 32; off; off >>= 1) p += __shfl_down(p, off, 64);
  if (lane == 0) l1[wv] = p;
}

// ---------------- single-block exclusive scan (CSR offsets) ----------------
__global__ __launch_bounds__(1024) void scan_kernel(const int* __restrict__ deg, int* __restrict__ offs,
                                                    int* __restrict__ cur, int N){
  __shared__ int wsums[16];
  __shared__ int carry_s;
  int tid = threadIdx.x;
  int lane = tid & 63, wid = tid >> 6;
  if (tid == 0) carry_s = 0;
  __syncthreads();
  for (int base = 0; base < N; base += 1024){
    int i = base + tid;
    int v = (i < N) ? deg[i] : 0;
    int x = v;
    #pragma unroll
    for (int off = 1; off < 64; off <<= 1){
      int y = __shfl_up(x, off, 64);
      if (lane >= off) x += y;
    }
    if (lane == 63) wsums[wid] = x;
    __syncthreads();
    if (wid == 0){
      int w = (lane < 16) ? wsums[lane] : 0;
      #pragma unroll
      for (int off = 1; off < 16; off <<= 1){
        int y = __shfl_up(w, off, 64);
        if (lane >= off) w += y;
      }
      if (lane < 16) wsums[lane] = w;
    }
    __syncthreads();
    int wexcl = (wid == 0) ? 0 : wsums[wid - 1];
    int incl = carry_s + wexcl + x;
    if (i < N){ offs[i] = incl - v; cur[i] = incl - v; }
    __syncthreads();
    if (tid == 1023) carry_s = incl;
    __syncthreads();
  }
  if (threadIdx.x == 0) offs[N] = carry_s;
}

// ---------------- scatter: CSR edge ids + compacted dst + compacted src ----------------
__global__ void scatter_kernel(const int* __restrict__ dst, const int* __restrict__ src,
                               int* __restrict__ cur, int* __restrict__ eids,
                               int* __restrict__ dstc, int* __restrict__ srcc, int E){
  int e = blockIdx.x * 256 + threadIdx.x;
  if (e < E){
    int d = dst[e];
    int pos = atomicAdd(&cur[d], 1);
    eids[pos] = e;
    dstc[pos] = d;
    srcc[pos] = src[e];
  }
}

// ---------------- MFMA node GEMM: C = act(A[M,K] @ W^T + bias) ----------------
template<int ACT>
__global__ __launch_bounds__(256) void mgemm_kernel(
    const float* __restrict__ A, const u16* __restrict__ Wb, const float* __restrict__ bias,
    float* __restrict__ C, int M, int K, int Nout, int Kpad)
{
  __shared__ __align__(16) u16 As[64][72];
  __shared__ __align__(16) u16 Ws[64][72];
  int tid = threadIdx.x;
  int m0 = blockIdx.y * 64, n0 = blockIdx.x * 64;
  int l = tid & 63, w = tid >> 6, quad = l >> 4, col = l & 15;

  ffrag acc[4];
  #pragma unroll
  for (int t = 0; t < 4; ++t){ acc[t].x = 0.f; acc[t].y = 0.f; acc[t].z = 0.f; acc[t].w = 0.f; }

  int nK = Kpad >> 6;
  for (int kc = 0; kc < nK; ++kc){
    int k0 = kc << 6;
    for (int idx = tid; idx < 64 * 16; idx += 256){
      int r = idx >> 4, c4 = idx & 15;
      int row = m0 + r, k = k0 + c4 * 4;
      float4 v = make_float4(0.f,0.f,0.f,0.f);
      if (row < M && k < K) v = *(const float4*)(A + (long)row * K + k);
      *(ushort4*)&As[r][c4 * 4] = make_ushort4(f2b(v.x), f2b(v.y), f2b(v.z), f2b(v.w));
    }
    for (int idx = tid; idx < 64 * 8; idx += 256){
      int r = idx >> 3, c = idx & 7;
      *(ulonglong2*)&Ws[r][c * 8] = *(const ulonglong2*)(Wb + (long)(n0 + r) * Kpad + k0 + c * 8);
    }
    __syncthreads();
    bfrag a0 = *(const bfrag*)&As[w * 16 + col][quad * 8];
    bfrag a1 = *(const bfrag*)&As[w * 16 + col][32 + quad * 8];
    #pragma unroll
    for (int t = 0; t < 4; ++t){
      bfrag b0 = *(const bfrag*)&Ws[t * 16 + col][quad * 8];
      bfrag b1 = *(const bfrag*)&Ws[t * 16 + col][32 + quad * 8];
      acc[t] = MFMA16(a0, b0, acc[t]);
      acc[t] = MFMA16(a1, b1, acc[t]);
    }
    __syncthreads();
  }

  #pragma unroll
  for (int t = 0; t < 4; ++t){
    int n = n0 + t * 16 + col;
    if (n >= Nout) continue;
    float bv = bias[n];
    #pragma unroll
    for (int r = 0; r < 4; ++r){
      int row = m0 + w * 16 + quad * 4 + r;
      if (row >= M) continue;
      float v = acc[t][r] + bv;
      if (ACT == 1) v = lrelu(v);
      C[(long)row * Nout + n] = v;
    }
  }
}

// ---------------- CSR edge kernel v3 ----------------
// 64 CSR positions/block. Xs separate from walk-stage (3 barriers). ex bf16 in stage col 200.
#define SSTR 202
__global__ __launch_bounds__(256) void edge_csr_kernel(
    const float* __restrict__ nf, const float* __restrict__ ef,
    const int* __restrict__ eids, const int* __restrict__ dstc, const int* __restrict__ srcc,
    const int* __restrict__ offs,
    const u16* __restrict__ Wbg, const float* __restrict__ be1,
    const float* __restrict__ We2, const float* __restrict__ be2,
    const float* __restrict__ l1,
    float* __restrict__ s_raw, float* __restrict__ denom, int E)
{
  __shared__ __align__(16) u16 Xs[64 * 72];      // 9216 B
  __shared__ __align__(16) u16 stage[64 * SSTR]; // 25856 B
  __shared__ u32 bw_s[208];                      // bias bf16 | w2hi bf16<<16
  __shared__ int nodef[64];                      // (n+1) | f1<<26 | f2<<27 ; 0 = invalid
  __shared__ int es[64], srcs[64];

  int tid = threadIdx.x;
  int j0 = blockIdx.x * 64;

  if (tid < 64){
    int j = j0 + tid;
    int valid = j < E;
    int e = valid ? eids[j] : 0;
    es[tid] = e;
    srcs[tid] = valid ? srcc[j] : 0;
    int n = valid ? dstc[j] : -1;
    int nn = (tid == 63 || j + 1 >= E) ? -2 : dstc[j + 1];
    int f1 = (valid && n != nn) ? 1 : 0;
    int f2 = 0;
    if (f1 && (offs[n] >= j0) && (offs[n + 1] <= j0 + 64)) f2 = 1;
    nodef[tid] = valid ? ((n + 1) | (f1 << 26) | (f2 << 27)) : 0;
  }
  if (tid < 208){
    float bv = (tid < G) ? be1[tid] : 0.f;
    float wv = (tid < G) ? We2[G + tid] : 0.f;
    bw_s[tid] = (u32)f2b(bv) | ((u32)f2b(wv) << 16);
  }
  __syncthreads();  // sync 1

  // X fill
  for (int idx = tid; idx < 64 * 8; idx += 256){
    int el = idx >> 3, c = idx & 7;
    float4 v = make_float4(0.f,0.f,0.f,0.f);
    if (j0 + el < E) v = *(const float4*)(nf + (long)srcs[el] * NDIM + c * 4);
    *(ushort4*)&Xs[el * 72 + c * 4] = make_ushort4(f2b(v.x), f2b(v.y), f2b(v.z), f2b(v.w));
  }
  for (int idx = tid; idx < 64 * EDIM; idx += 256){
    int el = idx / EDIM, k = idx - el * EDIM;
    float v = 0.f;
    if (j0 + el < E) v = ef[(long)es[el] * EDIM + k];
    Xs[el * 72 + NDIM + k] = f2b(v);
  }
  for (int idx = tid; idx < 64 * 13; idx += 256){
    int el = idx / 13, kk = idx - el * 13;
    Xs[el * 72 + KIN + kk] = 0;
  }
  __syncthreads();  // sync 2

  int l = tid & 63, w = tid >> 6;
  int quad = l >> 4, col = l & 15;
  int m0 = w * 16;

  bfrag a0 = *(const bfrag*)&Xs[(m0 + col) * 72 + quad * 8];
  bfrag a1 = *(const bfrag*)&Xs[(m0 + col) * 72 + 32 + quad * 8];

  ffrag acc[13];
  #pragma unroll
  for (int t = 0; t < 13; ++t){ acc[t].x = 0.f; acc[t].y = 0.f; acc[t].z = 0.f; acc[t].w = 0.f; }
  #pragma unroll
  for (int t = 0; t < 13; ++t){
    bfrag b0 = *(const bfrag*)(Wbg + (t * 16 + col) * 64 + quad * 8);
    bfrag b1 = *(const bfrag*)(Wbg + (t * 16 + col) * 64 + 32 + quad * 8);
    acc[t] = MFMA16(a0, b0, acc[t]);
    acc[t] = MFMA16(a1, b1, acc[t]);
  }

  // logit partials; butterfly leaves group sum in every lane
  float pl[4] = {0.f, 0.f, 0.f, 0.f};
  #pragma unroll
  for (int t = 0; t < 13; ++t){
    int g = t * 16 + col;
    u32 bw = bw_s[g];
    float bv = b2f((u16)(bw & 0xFFFF)), wv = b2f((u16)(bw >> 16));
    #pragma unroll
    for (int r = 0; r < 4; ++r)
      pl[r] += wv * lrelu(acc[t][r] + bv);
  }
  #pragma unroll
  for (int r = 0; r < 4; ++r){
    pl[r] += __shfl_xor(pl[r], 1, 16);
    pl[r] += __shfl_xor(pl[r], 2, 16);
    pl[r] += __shfl_xor(pl[r], 4, 16);
    pl[r] += __shfl_xor(pl[r], 8, 16);
  }
  float exv[4];
  #pragma unroll
  for (int r = 0; r < 4; ++r){
    int el = m0 + quad * 4 + r;
    int enc = nodef[el];
    float ex = 0.f;
    if (enc){
      int n = (enc & 0x03FFFFFF) - 1;
      float lg = lrelu(pl[r] + l1[n] + be2[0]);
      ex = __expf(lg);
    }
    exv[r] = ex;
  }

  // staging (stage region disjoint from Xs -> no barrier needed before writes)
  #pragma unroll
  for (int t = 0; t < 13; ++t){
    int g = t * 16 + col;
    u32 bw = bw_s[g];
    float bv = b2f((u16)(bw & 0xFFFF));
    #pragma unroll
    for (int r = 0; r < 4; ++r){
      int el = m0 + quad * 4 + r;
      if (g < G) stage[el * SSTR + g] = f2b(lrelu(acc[t][r] + bv) * exv[r]);
      else if (g == 200) stage[el * SSTR + 200] = f2b(exv[r]);
    }
  }
  __syncthreads();  // sync 3

  // segmented walk: tid 0..199 -> s_raw cols; tid 200 -> denom (ex bf16 from col 200)
  if (tid <= 200){
    float run = 0.f;
    #pragma unroll 4
    for (int r = 0; r < 64; ++r){
      run += b2f(stage[r * SSTR + tid]);
      int enc = nodef[r];
      if (enc & (1 << 26)){
        int n = (enc & 0x03FFFFFF) - 1;
        float* pd = (tid < G) ? (s_raw + (long)n * G + tid) : (denom + n);
        if (enc & (1 << 27)) *pd = run; else atomicAdd(pd, run);
        run = 0.f;
      }
    }
  }
}

// ---------------- fused ctx + GRU kernel ----------------
// Per 64-row block: stage [s*invd | hv] bf16 in X[64][416]; phase1 ctx=elu(s@Wet^T+bet) written
// in-place over cols 0..199; phase2 r,z (K=416 over [ctx|hv]), inn (K=224), hn (frags 6..12),
// then GRU + relu epilogue -> out. Weight zero-padding kills junk K-columns.
__global__ __launch_bounds__(256) void ctxgru_kernel(
    const float* __restrict__ s_raw, const float* __restrict__ hv, const float* __restrict__ denom,
    const u16* __restrict__ Wet2, const u16* __restrict__ Wrz,
    const u16* __restrict__ Winn, const u16* __restrict__ Whn,
    const float* __restrict__ bet, const float* __restrict__ b_ih, const float* __restrict__ b_hh,
    float* __restrict__ out, int M)
{
  __shared__ __align__(16) u16 X[64 * 416];
  __shared__ float invds[64];
  int tid = threadIdx.x;
  int m0 = blockIdx.x * 64;

  if (tid < 64){
    float dn = (m0 + tid < M) ? denom[m0 + tid] : 0.f;
    invds[tid] = dn > 0.f ? 1.f / dn : 0.f;
  }
  __syncthreads();

  for (int idx = tid; idx < 64 * 50; idx += 256){
    int r = idx / 50, c = idx % 50;
    int row = m0 + r;
    float4 v = make_float4(0.f,0.f,0.f,0.f), h = make_float4(0.f,0.f,0.f,0.f);
    if (row < M){
      v = *(const float4*)(s_raw + (long)row * G + c * 4);
      h = *(const float4*)(hv + (long)row * G + c * 4);
    }
    float iv = invds[r];
    *(ushort4*)&X[r * 416 + c * 4] = make_ushort4(f2b(v.x*iv), f2b(v.y*iv), f2b(v.z*iv), f2b(v.w*iv));
    *(ushort4*)&X[r * 416 + 208 + c * 4] = make_ushort4(f2b(h.x), f2b(h.y), f2b(h.z), f2b(h.w));
  }
  for (int idx = tid; idx < 64 * 4; idx += 256){
    int r = idx / 4, q = idx % 4;
    int base = (q < 2) ? (200 + q * 4) : (408 + (q - 2) * 4);
    *(ushort4*)&X[r * 416 + base] = make_ushort4(0,0,0,0);
  }
  __syncthreads();

  int l = tid & 63, w = tid >> 6, quad = l >> 4, col = l & 15;
  int rowbase = w * 16;

  // ---- phase 1: ctx ----
  bfrag a1[7];
  #pragma unroll
  for (int j = 0; j < 7; ++j) a1[j] = *(const bfrag*)&X[(rowbase + col) * 416 + j * 32 + quad * 8];

  for (int st = 0; st < 13; ++st){
    int n = st * 16 + col;   // 0..207
    ffrag acc; acc.x = 0.f; acc.y = 0.f; acc.z = 0.f; acc.w = 0.f;
    #pragma unroll
    for (int j = 0; j < 7; ++j){
      bfrag b = *(const bfrag*)(Wet2 + (long)n * 224 + j * 32 + quad * 8);
      acc = MFMA16(a1[j], b, acc);
    }
    if (n < G){
      float bv = bet[n];
      #pragma unroll
      for (int r = 0; r < 4; ++r){
        int lr = rowbase + quad * 4 + r;
        float gate = invds[lr] > 0.f ? 1.f : 0.f;
        float v = acc[r] + gate * bv;
        v = (v > 0.f) ? v : (__expf(v) - 1.f);
        X[lr * 416 + n] = f2b(v);   // own-wave rows only
      }
    }
  }
  __syncthreads();

  // ---- phase 2: gates + GRU ----
  bfrag a2[13];
  #pragma unroll
  for (int j = 0; j < 13; ++j) a2[j] = *(const bfrag*)&X[(rowbase + col) * 416 + j * 32 + quad * 8];

  for (int st = 0; st < 13; ++st){
    int n = st * 16 + col;
    ffrag ar, az, ai, ah;
    ar.x=ar.y=ar.z=ar.w=0.f; az.x=az.y=az.z=az.w=0.f;
    ai.x=ai.y=ai.z=ai.w=0.f; ah.x=ah.y=ah.z=ah.w=0.f;
    #pragma unroll
    for (int j = 0; j < 13; ++j){
      bfrag br_ = *(const bfrag*)(Wrz + (long)n * 416 + j * 32 + quad * 8);
      ar = MFMA16(a2[j], br_, ar);
      bfrag bz_ = *(const bfrag*)(Wrz + (long)(208 + n) * 416 + j * 32 + quad * 8);
      az = MFMA16(a2[j], bz_, az);
    }
    #pragma unroll
    for (int j = 0; j < 7; ++j){
      bfrag bi_ = *(const bfrag*)(Winn + (long)n * 224 + j * 32 + quad * 8);
      ai = MFMA16(a2[j], bi_, ai);
      bfrag bh_ = *(const bfrag*)(Whn + (long)n * 224 + j * 32 + quad * 8);
      ah = MFMA16(a2[j + 6], bh_, ah);
    }
    if (n < G){
      float br = b_ih[n] + b_hh[n];
      float bz = b_ih[G + n] + b_hh[G + n];
      float bi = b_ih[2 * G + n];
      float bh = b_hh[2 * G + n];
      #pragma unroll
      for (int r = 0; r < 4; ++r){
        int lr = rowbase + quad * 4 + r;
        int row = m0 + lr;
        if (row < M){
          float rg = 1.f / (1.f + __expf(-(ar[r] + br)));
          float zg = 1.f / (1.f + __expf(-(az[r] + bz)));
          float ng = tanhf(ai[r] + bi + rg * (ah[r] + bh));
          float hvv = b2f(X[lr * 416 + 208 + n]);
          float h = (1.f - zg) * ng + zg * hvv;
          out[(long)row * G + n] = h > 0.f ? h : 0.f;
        }
      }
    }
  }
}

extern "C" void kernel_launch(void* const* d_in, const int* in_sizes, int n_in,
                              void* d_out, int out_size, void* d_ws, size_t ws_size,
                              hipStream_t stream)
{
  const float* nf   = (const float*)d_in[0];
  const float* ef   = (const float*)d_in[1];
  const int*   src  = (const int*)d_in[2];
  const int*   dst  = (const int*)d_in[3];
  const float* Wn   = (const float*)d_in[4];
  const float* bn   = (const float*)d_in[5];
  const float* We1  = (const float*)d_in[6];
  const float* be1  = (const float*)d_in[7];
  const float* We2  = (const float*)d_in[8];
  const float* be2  = (const float*)d_in[9];
  const float* Wet  = (const float*)d_in[10];
  const float* bet  = (const float*)d_in[11];
  const float* W_ih = (const float*)d_in[12];
  const float* b_ih = (const float*)d_in[13];
  const float* W_hh = (const float*)d_in[14];
  const float* b_hh = (const float*)d_in[15];
  int N = in_sizes[0] / NDIM;   // 25000
  int E = in_sizes[2];          // 500000
  float* out = (float*)d_out;

  char* p = (char*)d_ws;
  auto alloc = [&](size_t b){ char* r = p; p += (b + 255) & ~(size_t)255; return r; };
  float* hv    = (float*)alloc((size_t)N * G * 4);
  float* s_raw = (float*)alloc((size_t)N * G * 4);
  float* denom = (float*)alloc((size_t)N * 4);
  int*   deg   = (int*)  alloc((size_t)N * 4);
  int*   offs  = (int*)  alloc((size_t)(N + 1) * 4);
  int*   cur   = (int*)  alloc((size_t)N * 4);
  int*   eids  = (int*)  alloc((size_t)E * 4);
  int*   dstc  = (int*)  alloc((size_t)E * 4);
  int*   srcc  = (int*)  alloc((size_t)E * 4);
  float* l1    = (float*)alloc((size_t)N * 4);
  u16*   Wbg   = (u16*)  alloc((size_t)208 * 64 * 2);
  u16*   Wnb   = (u16*)  alloc((size_t)256 * 64 * 2);
  u16*   Wet2  = (u16*)  alloc((size_t)208 * 224 * 2);
  u16*   Wrz   = (u16*)  alloc((size_t)2 * 208 * 416 * 2);
  u16*   Winn  = (u16*)  alloc((size_t)208 * 224 * 2);
  u16*   Whn   = (u16*)  alloc((size_t)208 * 224 * 2);

  int eb = (E + 255) / 256;
  int mb = (N + 63) / 64;

  zero_kernel<<<dim3((N * G + 255) / 256), dim3(256), 0, stream>>>(s_raw, denom, deg, N);
  prep_w_kernel<<<dim3((208 * 64 + 255) / 256), dim3(256), 0, stream>>>(We1, Wbg, G, KIN, 208, 64);
  prep_w_kernel<<<dim3((256 * 64 + 255) / 256), dim3(256), 0, stream>>>(Wn, Wnb, G, NDIM, 256, 64);
  prep_w_kernel<<<dim3((208 * 224 + 255) / 256), dim3(256), 0, stream>>>(Wet, Wet2, G, G, 208, 224);
  prep_wrz_kernel<<<dim3((2 * 208 * 416 + 255) / 256), dim3(256), 0, stream>>>(W_ih, W_hh, Wrz);
  prep_winn_kernel<<<dim3((208 * 224 + 255) / 256), dim3(256), 0, stream>>>(W_ih, Winn);
  prep_whn_kernel<<<dim3((208 * 224 + 255) / 256), dim3(256), 0, stream>>>(W_hh, Whn);
  deghist_kernel<<<dim3(eb), dim3(256), 0, stream>>>(dst, deg, E);
  scan_kernel<<<dim3(1), dim3(1024), 0, stream>>>(deg, offs, cur, N);
  scatter_kernel<<<dim3(eb), dim3(256), 0, stream>>>(dst, src, cur, eids, dstc, srcc, E);

  // hv = lrelu(nf @ Wn^T + bn)
  mgemm_kernel<1><<<dim3(4, mb), dim3(256), 0, stream>>>(nf, Wnb, bn, hv, N, NDIM, G, 64);
  l1_kernel<<<dim3((N * 64 + 255) / 256), dim3(256), 0, stream>>>(hv, We2, l1, N);
  // CSR edge pass: s_raw, denom
  edge_csr_kernel<<<dim3((E + 63) / 64), dim3(256), 0, stream>>>(nf, ef, eids, dstc, srcc, offs,
                                                                 Wbg, be1, We2, be2, l1, s_raw, denom, E);
  // fused ctx + GRU -> out
  ctxgru_kernel<<<dim3(mb), dim3(256), 0, stream>>>(s_raw, hv, denom, Wet2, Wrz, Winn, Whn,
                                                    bet, b_ih, b_hh, out, N);
}

// Round 9
// 456.637 us; speedup vs baseline: 1.4489x; 1.0844x over previous
//
#include <hip/hip_runtime.h>
#include <hip/hip_bf16.h>

#define G 200
#define NDIM 32
#define EDIM 19
#define KIN 51  // NDIM + EDIM

typedef unsigned short u16;
typedef unsigned int u32;
typedef unsigned long long u64;

typedef __attribute__((ext_vector_type(8))) short bfrag;   // 8 bf16 (4 VGPRs)
typedef __attribute__((ext_vector_type(4))) float ffrag;   // 4 fp32 acc

__device__ __forceinline__ float lrelu(float x){ return x > 0.f ? x : 0.01f*x; }
__device__ __forceinline__ u16 f2b(float x){ u32 u = __float_as_uint(x); return (u16)((u + 0x7fffu + ((u >> 16) & 1u)) >> 16); }
__device__ __forceinline__ float b2f(u16 x){ return __uint_as_float(((u32)x) << 16); }

#define MFMA16(a, b, c) __builtin_amdgcn_mfma_f32_16x16x32_bf16(a, b, c, 0, 0, 0)

// ---------------- zero: s_raw [N*G], denom, deg, l1 ----------------
__global__ void zero_kernel(float* __restrict__ s_raw, float* __restrict__ denom,
                            int* __restrict__ deg, float* __restrict__ l1, int N){
  int i = blockIdx.x * 256 + threadIdx.x;
  if (i < N * G) s_raw[i] = 0.f;
  if (i < N){ denom[i] = 0.f; deg[i] = 0; l1[i] = 0.f; }
}

// ---------------- one fused weight-prep kernel (all 6 layouts) ----------------
__global__ void prep_all_kernel(const float* __restrict__ We1, const float* __restrict__ Wn,
                                const float* __restrict__ Wet, const float* __restrict__ Wih,
                                const float* __restrict__ Whh,
                                u16* __restrict__ Wbg, u16* __restrict__ Wnb, u16* __restrict__ Wet2,
                                u16* __restrict__ Wrz, u16* __restrict__ Winn, u16* __restrict__ Whn){
  int idx = blockIdx.x * 256 + threadIdx.x;
  const int s0 = 208 * 64, s1 = 256 * 64, s2 = 208 * 224, s3 = 2 * 208 * 416, s4 = 208 * 224, s5 = 208 * 224;
  if (idx < s0){
    int r = idx >> 6, k = idx & 63;
    Wbg[idx] = f2b((r < G && k < KIN) ? We1[r * KIN + k] : 0.f);
    return;
  }
  idx -= s0;
  if (idx < s1){
    int r = idx >> 6, k = idx & 63;
    Wnb[idx] = f2b((r < G && k < NDIM) ? Wn[r * NDIM + k] : 0.f);
    return;
  }
  idx -= s1;
  if (idx < s2){
    int r = idx / 224, k = idx % 224;
    Wet2[idx] = f2b((r < G && k < G) ? Wet[r * G + k] : 0.f);
    return;
  }
  idx -= s2;
  if (idx < s3){
    int g = idx / (208 * 416), rem = idx % (208 * 416);
    int r = rem / 416, k = rem % 416;
    float v = 0.f;
    if (r < G){
      int row = g * G + r;
      if (k < G) v = Wih[row * G + k];
      else if (k >= 208 && k < 408) v = Whh[row * G + (k - 208)];
    }
    Wrz[idx] = f2b(v);
    return;
  }
  idx -= s3;
  if (idx < s4){
    int r = idx / 224, k = idx % 224;
    Winn[idx] = f2b((r < G && k < G) ? Wih[(2 * G + r) * G + k] : 0.f);
    return;
  }
  idx -= s4;
  if (idx < s5){
    int r = idx / 224, kk = idx % 224;
    Whn[idx] = f2b((r < G && kk >= 16 && kk < 216) ? Whh[(2 * G + r) * G + (kk - 16)] : 0.f);
  }
}

// ---------------- degree histogram ----------------
__global__ void deghist_kernel(const int* __restrict__ dst, int* __restrict__ deg, int E){
  int e = blockIdx.x * 256 + threadIdx.x;
  if (e < E) atomicAdd(&deg[dst[e]], 1);
}

// ---------------- single-block exclusive scan (CSR offsets) ----------------
__global__ __launch_bounds__(1024) void scan_kernel(const int* __restrict__ deg, int* __restrict__ offs,
                                                    int* __restrict__ cur, int N){
  __shared__ int wsums[16];
  __shared__ int carry_s;
  int tid = threadIdx.x;
  int lane = tid & 63, wid = tid >> 6;
  if (tid == 0) carry_s = 0;
  __syncthreads();
  for (int base = 0; base < N; base += 1024){
    int i = base + tid;
    int v = (i < N) ? deg[i] : 0;
    int x = v;
    #pragma unroll
    for (int off = 1; off < 64; off <<= 1){
      int y = __shfl_up(x, off, 64);
      if (lane >= off) x += y;
    }
    if (lane == 63) wsums[wid] = x;
    __syncthreads();
    if (wid == 0){
      int w = (lane < 16) ? wsums[lane] : 0;
      #pragma unroll
      for (int off = 1; off < 16; off <<= 1){
        int y = __shfl_up(w, off, 64);
        if (lane >= off) w += y;
      }
      if (lane < 16) wsums[lane] = w;
    }
    __syncthreads();
    int wexcl = (wid == 0) ? 0 : wsums[wid - 1];
    int incl = carry_s + wexcl + x;
    if (i < N){ offs[i] = incl - v; cur[i] = incl - v; }
    __syncthreads();
    if (tid == 1023) carry_s = incl;
    __syncthreads();
  }
  if (threadIdx.x == 0) offs[N] = carry_s;
}

// ---------------- scatter: CSR edge ids + compacted dst + compacted src ----------------
__global__ void scatter_kernel(const int* __restrict__ dst, const int* __restrict__ src,
                               int* __restrict__ cur, int* __restrict__ eids,
                               int* __restrict__ dstc, int* __restrict__ srcc, int E){
  int e = blockIdx.x * 256 + threadIdx.x;
  if (e < E){
    int d = dst[e];
    int pos = atomicAdd(&cur[d], 1);
    eids[pos] = e;
    dstc[pos] = d;
    srcc[pos] = src[e];
  }
}

// ---------------- hv GEMM + fused l1 partials: hv = lrelu(nf@Wn^T+bn); l1 += We2[.]·hv ----------------
__global__ __launch_bounds__(256) void hvgemm_kernel(
    const float* __restrict__ nf, const u16* __restrict__ Wnb, const float* __restrict__ bn,
    const float* __restrict__ We2, float* __restrict__ hv, float* __restrict__ l1, int M)
{
  __shared__ __align__(16) u16 As[64][72];
  __shared__ __align__(16) u16 Ws[64][72];
  int tid = threadIdx.x;
  int m0 = blockIdx.y * 64, n0 = blockIdx.x * 64;
  int l = tid & 63, w = tid >> 6, quad = l >> 4, col = l & 15;

  for (int idx = tid; idx < 64 * 16; idx += 256){
    int r = idx >> 4, c4 = idx & 15;
    int row = m0 + r, k = c4 * 4;
    float4 v = make_float4(0.f,0.f,0.f,0.f);
    if (row < M && k < NDIM) v = *(const float4*)(nf + (long)row * NDIM + k);
    *(ushort4*)&As[r][c4 * 4] = make_ushort4(f2b(v.x), f2b(v.y), f2b(v.z), f2b(v.w));
  }
  for (int idx = tid; idx < 64 * 8; idx += 256){
    int r = idx >> 3, c = idx & 7;
    *(ulonglong2*)&Ws[r][c * 8] = *(const ulonglong2*)(Wnb + (long)(n0 + r) * 64 + c * 8);
  }
  __syncthreads();
  bfrag a0 = *(const bfrag*)&As[w * 16 + col][quad * 8];
  bfrag a1 = *(const bfrag*)&As[w * 16 + col][32 + quad * 8];
  ffrag acc[4];
  #pragma unroll
  for (int t = 0; t < 4; ++t){ acc[t].x = 0.f; acc[t].y = 0.f; acc[t].z = 0.f; acc[t].w = 0.f; }
  #pragma unroll
  for (int t = 0; t < 4; ++t){
    bfrag b0 = *(const bfrag*)&Ws[t * 16 + col][quad * 8];
    bfrag b1 = *(const bfrag*)&Ws[t * 16 + col][32 + quad * 8];
    acc[t] = MFMA16(a0, b0, acc[t]);
    acc[t] = MFMA16(a1, b1, acc[t]);
  }
  float lp[4] = {0.f, 0.f, 0.f, 0.f};
  #pragma unroll
  for (int t = 0; t < 4; ++t){
    int n = n0 + t * 16 + col;
    float bv = (n < G) ? bn[n] : 0.f;
    float wv = (n < G) ? We2[n] : 0.f;
    #pragma unroll
    for (int r = 0; r < 4; ++r){
      int row = m0 + w * 16 + quad * 4 + r;
      float v = lrelu(acc[t][r] + bv);
      lp[r] += wv * v;
      if (n < G && row < M) hv[(long)row * G + n] = v;
    }
  }
  #pragma unroll
  for (int r = 0; r < 4; ++r){
    lp[r] += __shfl_xor(lp[r], 1, 16);
    lp[r] += __shfl_xor(lp[r], 2, 16);
    lp[r] += __shfl_xor(lp[r], 4, 16);
    lp[r] += __shfl_xor(lp[r], 8, 16);
  }
  if (col == 0){
    #pragma unroll
    for (int r = 0; r < 4; ++r){
      int row = m0 + w * 16 + quad * 4 + r;
      if (row < M) atomicAdd(&l1[row], lp[r]);
    }
  }
}

// ---------------- CSR edge kernel v4: one-acc he1 MFMA + MFMA segment reduction ----------------
// Phase 1: per wave one live acc; he1 (pre-ex) bf16 staged TRANSPOSED stageT[g][el], stride 72.
// Phase 2: segment-sum as MFMA: out[seg][g] = sum_k (Ind[seg][k]*ex[k]) * he1T[g][k]; row 200 = ones -> denom.
#define SST 72
__global__ __launch_bounds__(256) void edge_csr_kernel(
    const float* __restrict__ nf, const float* __restrict__ ef,
    const int* __restrict__ eids, const int* __restrict__ dstc, const int* __restrict__ srcc,
    const int* __restrict__ offs,
    const u16* __restrict__ Wbg, const float* __restrict__ be1,
    const float* __restrict__ We2, const float* __restrict__ be2,
    const float* __restrict__ l1,
    float* __restrict__ s_raw, float* __restrict__ denom, int E)
{
  __shared__ __align__(16) u16 shm[208 * SST];  // Xs view [64][72] (first 4608) UNION stageT [208][72]
  __shared__ u32 bw_s[208];
  __shared__ int node_s[64], es[64], srcs[64], segnode[64];
  __shared__ __align__(16) u16 exb[64];
  __shared__ __align__(8) unsigned char segb[64];
  __shared__ int Svar;

  int tid = threadIdx.x;
  int j0 = blockIdx.x * 64;

  if (tid < 64){
    int j = j0 + tid;
    int valid = j < E;
    int e = valid ? eids[j] : 0;
    es[tid] = e;
    srcs[tid] = valid ? srcc[j] : 0;
    int n = valid ? dstc[j] : -1;
    node_s[tid] = n;
    int nn = (tid == 63 || j + 1 >= E) ? -2 : dstc[j + 1];
    int f1 = (valid && n != nn) ? 1 : 0;
    int f2 = 0;
    if (f1 && offs[n] >= j0 && offs[n + 1] <= j0 + 64) f2 = 1;
    u64 em = __ballot(f1 != 0);
    int seg = (int)__popcll(em & ((1ull << tid) - 1ull));
    segb[tid] = (unsigned char)seg;
    if (f1) segnode[seg] = (n << 1) | f2;
    if (tid == 0) Svar = (int)__popcll(em);
  }
  if (tid < 208){
    float bv = (tid < G) ? be1[tid] : 0.f;
    float wv = (tid < G) ? We2[G + tid] : 0.f;
    bw_s[tid] = (u32)f2b(bv) | ((u32)f2b(wv) << 16);
  }
  __syncthreads();  // sync 1: meta ready

  // X fill (Xs view, stride 72)
  for (int idx = tid; idx < 64 * 8; idx += 256){
    int el = idx >> 3, c = idx & 7;
    float4 v = make_float4(0.f,0.f,0.f,0.f);
    if (j0 + el < E) v = *(const float4*)(nf + (long)srcs[el] * NDIM + c * 4);
    *(ushort4*)&shm[el * SST + c * 4] = make_ushort4(f2b(v.x), f2b(v.y), f2b(v.z), f2b(v.w));
  }
  for (int idx = tid; idx < 64 * EDIM; idx += 256){
    int el = idx / EDIM, k = idx - el * EDIM;
    float v = 0.f;
    if (j0 + el < E) v = ef[(long)es[el] * EDIM + k];
    shm[el * SST + NDIM + k] = f2b(v);
  }
  for (int idx = tid; idx < 64 * 13; idx += 256){
    int el = idx / 13, kk = idx - el * 13;
    shm[el * SST + KIN + kk] = 0;
  }
  __syncthreads();  // sync 2: X ready

  int l = tid & 63, w = tid >> 6;
  int quad = l >> 4, col = l & 15;
  int m0 = w * 16;

  bfrag a0 = *(const bfrag*)&shm[(m0 + col) * SST + quad * 8];
  bfrag a1 = *(const bfrag*)&shm[(m0 + col) * SST + 32 + quad * 8];
  __syncthreads();  // sync 3: all Xs reads done; stage region writable

  if (tid < 64) shm[200 * SST + tid] = 0x3F80;  // ones row (for denom)

  // ---- phase 1: he1 tiles, ONE live acc; transposed staging + logit partials ----
  float pl[4] = {0.f, 0.f, 0.f, 0.f};
  #pragma unroll
  for (int t = 0; t < 13; ++t){
    bfrag b0 = *(const bfrag*)(Wbg + (t * 16 + col) * 64 + quad * 8);
    bfrag b1 = *(const bfrag*)(Wbg + (t * 16 + col) * 64 + 32 + quad * 8);
    ffrag acc; acc.x = 0.f; acc.y = 0.f; acc.z = 0.f; acc.w = 0.f;
    acc = MFMA16(a0, b0, acc);
    acc = MFMA16(a1, b1, acc);
    int g = t * 16 + col;
    u32 bw = bw_s[g];
    float bv = b2f((u16)(bw & 0xFFFF)), wv = b2f((u16)(bw >> 16));
    float v0 = lrelu(acc.x + bv), v1 = lrelu(acc.y + bv);
    float v2 = lrelu(acc.z + bv), v3 = lrelu(acc.w + bv);
    pl[0] += wv * v0; pl[1] += wv * v1; pl[2] += wv * v2; pl[3] += wv * v3;
    if (g < G)
      *(ushort4*)&shm[g * SST + m0 + quad * 4] = make_ushort4(f2b(v0), f2b(v1), f2b(v2), f2b(v3));
  }
  #pragma unroll
  for (int r = 0; r < 4; ++r){
    pl[r] += __shfl_xor(pl[r], 1, 16);
    pl[r] += __shfl_xor(pl[r], 2, 16);
    pl[r] += __shfl_xor(pl[r], 4, 16);
    pl[r] += __shfl_xor(pl[r], 8, 16);
  }
  if (col == 0){
    #pragma unroll
    for (int r = 0; r < 4; ++r){
      int el = m0 + quad * 4 + r;
      float ex = 0.f;
      if (j0 + el < E){
        int n = node_s[el];
        float lg = lrelu(pl[r] + l1[n] + be2[0]);
        ex = __expf(lg);
      }
      exb[el] = f2b(ex);
    }
  }
  __syncthreads();  // sync 4: stage + exb ready

  // ---- phase 2: MFMA segment reduction ----
  int S = Svar;
  for (int mt = 0; mt * 16 < S; ++mt){
    int m = mt * 16 + col;
    u64 sb0 = *(const u64*)&segb[quad * 8];
    u64 sb1 = *(const u64*)&segb[32 + quad * 8];
    ulonglong2 ew0 = *(const ulonglong2*)&exb[quad * 8];
    ulonglong2 ew1 = *(const ulonglong2*)&exb[32 + quad * 8];
    bfrag A0, A1;
    #pragma unroll
    for (int jj = 0; jj < 8; ++jj){
      int s0i = (int)((sb0 >> (8 * jj)) & 0xFF);
      int s1i = (int)((sb1 >> (8 * jj)) & 0xFF);
      u64 w0 = (jj < 4) ? ew0.x : ew0.y;
      u64 w1 = (jj < 4) ? ew1.x : ew1.y;
      u16 e0 = (u16)(w0 >> (16 * (jj & 3)));
      u16 e1 = (u16)(w1 >> (16 * (jj & 3)));
      A0[jj] = (s0i == m) ? (short)e0 : (short)0;
      A1[jj] = (s1i == m) ? (short)e1 : (short)0;
    }
    int cnt = (w == 3) ? 4 : 3;
    for (int i = 0; i < cnt; ++i){
      int t = w * 3 + i;   // waves 0..2: 3 tiles; wave 3: tiles 9..12
      bfrag b0 = *(const bfrag*)&shm[(t * 16 + col) * SST + quad * 8];
      bfrag b1 = *(const bfrag*)&shm[(t * 16 + col) * SST + 32 + quad * 8];
      ffrag acc; acc.x = 0.f; acc.y = 0.f; acc.z = 0.f; acc.w = 0.f;
      acc = MFMA16(A0, b0, acc);
      acc = MFMA16(A1, b1, acc);
      int g = t * 16 + col;
      #pragma unroll
      for (int r = 0; r < 4; ++r){
        int seg = mt * 16 + quad * 4 + r;
        if (seg < S && g <= 200){
          int enc = segnode[seg];
          int nd = enc >> 1;
          float v = acc[r];
          float* pd = (g < G) ? (s_raw + (long)nd * G + g) : (denom + nd);
          if (enc & 1) *pd = v; else atomicAdd(pd, v);
        }
      }
    }
  }
}

// ---------------- fused ctx + GRU kernel (round-8, verified) ----------------
__global__ __launch_bounds__(256) void ctxgru_kernel(
    const float* __restrict__ s_raw, const float* __restrict__ hv, const float* __restrict__ denom,
    const u16* __restrict__ Wet2, const u16* __restrict__ Wrz,
    const u16* __restrict__ Winn, const u16* __restrict__ Whn,
    const float* __restrict__ bet, const float* __restrict__ b_ih, const float* __restrict__ b_hh,
    float* __restrict__ out, int M)
{
  __shared__ __align__(16) u16 X[64 * 416];
  __shared__ float invds[64];
  int tid = threadIdx.x;
  int m0 = blockIdx.x * 64;

  if (tid < 64){
    float dn = (m0 + tid < M) ? denom[m0 + tid] : 0.f;
    invds[tid] = dn > 0.f ? 1.f / dn : 0.f;
  }
  __syncthreads();

  for (int idx = tid; idx < 64 * 50; idx += 256){
    int r = idx / 50, c = idx % 50;
    int row = m0 + r;
    float4 v = make_float4(0.f,0.f,0.f,0.f), h = make_float4(0.f,0.f,0.f,0.f);
    if (row < M){
      v = *(const float4*)(s_raw + (long)row * G + c * 4);
      h = *(const float4*)(hv + (long)row * G + c * 4);
    }
    float iv = invds[r];
    *(ushort4*)&X[r * 416 + c * 4] = make_ushort4(f2b(v.x*iv), f2b(v.y*iv), f2b(v.z*iv), f2b(v.w*iv));
    *(ushort4*)&X[r * 416 + 208 + c * 4] = make_ushort4(f2b(h.x), f2b(h.y), f2b(h.z), f2b(h.w));
  }
  for (int idx = tid; idx < 64 * 4; idx += 256){
    int r = idx / 4, q = idx % 4;
    int base = (q < 2) ? (200 + q * 4) : (408 + (q - 2) * 4);
    *(ushort4*)&X[r * 416 + base] = make_ushort4(0,0,0,0);
  }
  __syncthreads();

  int l = tid & 63, w = tid >> 6, quad = l >> 4, col = l & 15;
  int rowbase = w * 16;

  // ---- phase 1: ctx ----
  bfrag a1[7];
  #pragma unroll
  for (int j = 0; j < 7; ++j) a1[j] = *(const bfrag*)&X[(rowbase + col) * 416 + j * 32 + quad * 8];

  for (int st = 0; st < 13; ++st){
    int n = st * 16 + col;
    ffrag acc; acc.x = 0.f; acc.y = 0.f; acc.z = 0.f; acc.w = 0.f;
    #pragma unroll
    for (int j = 0; j < 7; ++j){
      bfrag b = *(const bfrag*)(Wet2 + (long)n * 224 + j * 32 + quad * 8);
      acc = MFMA16(a1[j], b, acc);
    }
    if (n < G){
      float bv = bet[n];
      #pragma unroll
      for (int r = 0; r < 4; ++r){
        int lr = rowbase + quad * 4 + r;
        float gate = invds[lr] > 0.f ? 1.f : 0.f;
        float v = acc[r] + gate * bv;
        v = (v > 0.f) ? v : (__expf(v) - 1.f);
        X[lr * 416 + n] = f2b(v);
      }
    }
  }
  __syncthreads();

  // ---- phase 2: gates + GRU ----
  bfrag a2[13];
  #pragma unroll
  for (int j = 0; j < 13; ++j) a2[j] = *(const bfrag*)&X[(rowbase + col) * 416 + j * 32 + quad * 8];

  for (int st = 0; st < 13; ++st){
    int n = st * 16 + col;
    ffrag ar, az, ai, ah;
    ar.x=ar.y=ar.z=ar.w=0.f; az.x=az.y=az.z=az.w=0.f;
    ai.x=ai.y=ai.z=ai.w=0.f; ah.x=ah.y=ah.z=ah.w=0.f;
    #pragma unroll
    for (int j = 0; j < 13; ++j){
      bfrag br_ = *(const bfrag*)(Wrz + (long)n * 416 + j * 32 + quad * 8);
      ar = MFMA16(a2[j], br_, ar);
      bfrag bz_ = *(const bfrag*)(Wrz + (long)(208 + n) * 416 + j * 32 + quad * 8);
      az = MFMA16(a2[j], bz_, az);
    }
    #pragma unroll
    for (int j = 0; j < 7; ++j){
      bfrag bi_ = *(const bfrag*)(Winn + (long)n * 224 + j * 32 + quad * 8);
      ai = MFMA16(a2[j], bi_, ai);
      bfrag bh_ = *(const bfrag*)(Whn + (long)n * 224 + j * 32 + quad * 8);
      ah = MFMA16(a2[j + 6], bh_, ah);
    }
    if (n < G){
      float br = b_ih[n] + b_hh[n];
      float bz = b_ih[G + n] + b_hh[G + n];
      float bi = b_ih[2 * G + n];
      float bh = b_hh[2 * G + n];
      #pragma unroll
      for (int r = 0; r < 4; ++r){
        int lr = rowbase + quad * 4 + r;
        int row = m0 + lr;
        if (row < M){
          float rg = 1.f / (1.f + __expf(-(ar[r] + br)));
          float zg = 1.f / (1.f + __expf(-(az[r] + bz)));
          float ng = tanhf(ai[r] + bi + rg * (ah[r] + bh));
          float hvv = b2f(X[lr * 416 + 208 + n]);
          float h = (1.f - zg) * ng + zg * hvv;
          out[(long)row * G + n] = h > 0.f ? h : 0.f;
        }
      }
    }
  }
}

extern "C" void kernel_launch(void* const* d_in, const int* in_sizes, int n_in,
                              void* d_out, int out_size, void* d_ws, size_t ws_size,
                              hipStream_t stream)
{
  const float* nf   = (const float*)d_in[0];
  const float* ef   = (const float*)d_in[1];
  const int*   src  = (const int*)d_in[2];
  const int*   dst  = (const int*)d_in[3];
  const float* Wn   = (const float*)d_in[4];
  const float* bn   = (const float*)d_in[5];
  const float* We1  = (const float*)d_in[6];
  const float* be1  = (const float*)d_in[7];
  const float* We2  = (const float*)d_in[8];
  const float* be2  = (const float*)d_in[9];
  const float* Wet  = (const float*)d_in[10];
  const float* bet  = (const float*)d_in[11];
  const float* W_ih = (const float*)d_in[12];
  const float* b_ih = (const float*)d_in[13];
  const float* W_hh = (const float*)d_in[14];
  const float* b_hh = (const float*)d_in[15];
  int N = in_sizes[0] / NDIM;   // 25000
  int E = in_sizes[2];          // 500000
  float* out = (float*)d_out;

  char* p = (char*)d_ws;
  auto alloc = [&](size_t b){ char* r = p; p += (b + 255) & ~(size_t)255; return r; };
  float* hv    = (float*)alloc((size_t)N * G * 4);
  float* s_raw = (float*)alloc((size_t)N * G * 4);
  float* denom = (float*)alloc((size_t)N * 4);
  int*   deg   = (int*)  alloc((size_t)N * 4);
  int*   offs  = (int*)  alloc((size_t)(N + 1) * 4);
  int*   cur   = (int*)  alloc((size_t)N * 4);
  int*   eids  = (int*)  alloc((size_t)E * 4);
  int*   dstc  = (int*)  alloc((size_t)E * 4);
  int*   srcc  = (int*)  alloc((size_t)E * 4);
  float* l1    = (float*)alloc((size_t)N * 4);
  u16*   Wbg   = (u16*)  alloc((size_t)208 * 64 * 2);
  u16*   Wnb   = (u16*)  alloc((size_t)256 * 64 * 2);
  u16*   Wet2  = (u16*)  alloc((size_t)208 * 224 * 2);
  u16*   Wrz   = (u16*)  alloc((size_t)2 * 208 * 416 * 2);
  u16*   Winn  = (u16*)  alloc((size_t)208 * 224 * 2);
  u16*   Whn   = (u16*)  alloc((size_t)208 * 224 * 2);

  int eb = (E + 255) / 256;
  int mb = (N + 63) / 64;
  const int prep_total = 208*64 + 256*64 + 208*224 + 2*208*416 + 208*224 + 208*224;

  zero_kernel<<<dim3((N * G + 255) / 256), dim3(256), 0, stream>>>(s_raw, denom, deg, l1, N);
  prep_all_kernel<<<dim3((prep_total + 255) / 256), dim3(256), 0, stream>>>(
      We1, Wn, Wet, W_ih, W_hh, Wbg, Wnb, Wet2, Wrz, Winn, Whn);
  deghist_kernel<<<dim3(eb), dim3(256), 0, stream>>>(dst, deg, E);
  scan_kernel<<<dim3(1), dim3(1024), 0, stream>>>(deg, offs, cur, N);
  scatter_kernel<<<dim3(eb), dim3(256), 0, stream>>>(dst, src, cur, eids, dstc, srcc, E);
  hvgemm_kernel<<<dim3(4, mb), dim3(256), 0, stream>>>(nf, Wnb, bn, We2, hv, l1, N);
  edge_csr_kernel<<<dim3((E + 63) / 64), dim3(256), 0, stream>>>(nf, ef, eids, dstc, srcc, offs,
                                                                 Wbg, be1, We2, be2, l1, s_raw, denom, E);
  ctxgru_kernel<<<dim3(mb), dim3(256), 0, stream>>>(s_raw, hv, denom, Wet2, Wrz, Winn, Whn,
                                                    bet, b_ih, b_hh, out, N);
}